// Round 3
// baseline (209.224 us; speedup 1.0000x reference)
//
#include <hip/hip_runtime.h>
#include <math.h>

#define BATCH 2048
#define LATENT 64
#define LOG_2PI 1.8378770664093453f
#define BETA_M1 5.0f
#define LN2 0.69314718055994530942f
// C2 = -0.5 * log2(e)
#define C2 (-0.72134752044448170368f)

// ws layout (floats):
//   Vt   [128][2048]    Vt[2l][j]=C2*inv, Vt[2l+1][j]=C2*m*inv  (row kernel, vector loads)
//   Vp   [64][2048][4]  packed (civ,cmv,cev,0) per (l,j)        (dim kernel, scalar loads)
//   Up   [128][2048]    Up[2l][i]=z2, Up[2l+1][i]=-2z           (row kernel, scalar loads)
//   CE   [2048]         CE[j] = sum_l cev
//   KLP  [2048]         per-sample KL partials
//   PP   [2][64][2048]  raw partial exp-sums over j-halves
//   RMP  [2][2048]      row-LSE partial max (log2 domain)
//   RSP  [2][2048]      row-LSE partial sum
//   PART [16]           8 tc partials + 8 kl partials
#define OFF_VT   0
#define OFF_VP   (128*BATCH)
#define OFF_UP   (OFF_VP + 64*BATCH*4)
#define OFF_CE   (OFF_UP + 128*BATCH)
#define OFF_KLP  (OFF_CE + BATCH)
#define OFF_PP   (OFF_KLP + BATCH)
#define OFF_RMP  (OFF_PP + 2*64*BATCH)
#define OFF_RSP  (OFF_RMP + 2*BATCH)
#define OFF_PART (OFF_RSP + 2*BATCH)

__global__ void precompute_kernel(const float* __restrict__ z,
                                  const float* __restrict__ z_mean,
                                  const float* __restrict__ z_logvar,
                                  float* __restrict__ ws) {
    int j = blockIdx.x;     // doubles as i for the U arrays
    int l = threadIdx.x;
    int idx = j * LATENT + l;
    float m  = z_mean[idx];
    float lv = z_logvar[idx];
    float iv = __expf(-lv);
    float civ = C2 * iv;
    float miv = m * iv;
    float cmv = C2 * miv;
    float cev = C2 * fmaf(m, miv, lv + LOG_2PI);

    ws[OFF_VT + (2*l)   * BATCH + j] = civ;
    ws[OFF_VT + (2*l+1) * BATCH + j] = cmv;
    float4 q = make_float4(civ, cmv, cev, 0.0f);
    *(float4*)(ws + OFF_VP + ((size_t)l * BATCH + j) * 4) = q;

    float zv = z[idx];
    ws[OFF_UP + (2*l)   * BATCH + j] = zv * zv;
    ws[OFF_UP + (2*l+1) * BATCH + j] = -2.0f * zv;

    float ce = cev;
    #pragma unroll
    for (int off = 32; off > 0; off >>= 1) ce += __shfl_xor(ce, off, 64);
    if (l == 0) ws[OFF_CE + j] = ce;

    float kp = fmaf(m, m, __expf(lv)) - lv - 1.0f;
    #pragma unroll
    for (int off = 32; off > 0; off >>= 1) kp += __shfl_xor(kp, off, 64);
    if (l == 0) ws[OFF_KLP + j] = kp;
}

// Per-dim partial exp-sums. Grid 1024 = 64 l * 8 i-chunks * 2 j-halves.
// All Vp loads block-uniform -> merged s_load_dwordx16 (one per 4 j).
__global__ __launch_bounds__(256) void dim_lse_kernel(const float* __restrict__ z,
                                                      float* __restrict__ ws) {
    int bx = blockIdx.x;
    int l  = bx >> 4;
    int ic = (bx >> 1) & 7;
    int ph = bx & 1;
    int i  = (ic << 8) + threadIdx.x;

    float zv  = z[i * LATENT + l];
    float z2  = zv * zv;
    float nz2 = -2.0f * zv;

    const float* __restrict__ vp = ws + OFF_VP + ((size_t)l * BATCH + ph * 1024) * 4;

    float s0 = 0.f, s1 = 0.f, s2 = 0.f, s3 = 0.f;
    float s4 = 0.f, s5 = 0.f, s6 = 0.f, s7 = 0.f;
    for (int jj = 0; jj < 1024; jj += 8) {
        const float* b = vp + jj * 4;
        float e0 = fmaf(z2, b[0],  fmaf(nz2, b[1],  b[2]));
        float e1 = fmaf(z2, b[4],  fmaf(nz2, b[5],  b[6]));
        float e2 = fmaf(z2, b[8],  fmaf(nz2, b[9],  b[10]));
        float e3 = fmaf(z2, b[12], fmaf(nz2, b[13], b[14]));
        float e4 = fmaf(z2, b[16], fmaf(nz2, b[17], b[18]));
        float e5 = fmaf(z2, b[20], fmaf(nz2, b[21], b[22]));
        float e6 = fmaf(z2, b[24], fmaf(nz2, b[25], b[26]));
        float e7 = fmaf(z2, b[28], fmaf(nz2, b[29], b[30]));
        s0 += __builtin_amdgcn_exp2f(e0);
        s1 += __builtin_amdgcn_exp2f(e1);
        s2 += __builtin_amdgcn_exp2f(e2);
        s3 += __builtin_amdgcn_exp2f(e3);
        s4 += __builtin_amdgcn_exp2f(e4);
        s5 += __builtin_amdgcn_exp2f(e5);
        s6 += __builtin_amdgcn_exp2f(e6);
        s7 += __builtin_amdgcn_exp2f(e7);
    }
    float s = ((s0 + s1) + (s2 + s3)) + ((s4 + s5) + (s6 + s7));
    ws[OFF_PP + ((size_t)ph * 64 + l) * BATCH + i] = s;   // raw sum; log applied later
}

// Row-sum GEMM + online LSE. Grid 256 = 128 i-blocks * 2 j-halves.
// U rows are scalar-loaded (block-uniform), V rows vector float4 (coalesced).
#define IT 16
__global__ __launch_bounds__(256) void row_lse_kernel(float* __restrict__ ws) {
    __shared__ float RM[IT][256];
    __shared__ float RS[IT][256];

    const float* __restrict__ Vt = ws + OFF_VT;
    const float* __restrict__ Up = ws + OFF_UP;
    const float* __restrict__ CE = ws + OFF_CE;

    int t  = threadIdx.x;
    int ib = blockIdx.x >> 1;
    int ph = blockIdx.x & 1;
    int i0 = ib * IT;
    int jb = ph * 1024 + 4 * t;

    float r[IT][4];
    #pragma unroll
    for (int i = 0; i < IT; ++i)
        r[i][0] = r[i][1] = r[i][2] = r[i][3] = 0.0f;

    for (int l = 0; l < LATENT; ++l) {
        float4 v0 = *(const float4*)(Vt + (2*l)   * BATCH + jb);
        float4 v1 = *(const float4*)(Vt + (2*l+1) * BATCH + jb);
        const float* __restrict__ u0 = Up + (2*l)   * BATCH + i0;  // uniform
        const float* __restrict__ u1 = Up + (2*l+1) * BATCH + i0;  // uniform
        #pragma unroll
        for (int i = 0; i < IT; ++i) {
            float a = u0[i];
            float b = u1[i];
            r[i][0] = fmaf(a, v0.x, r[i][0]);
            r[i][1] = fmaf(a, v0.y, r[i][1]);
            r[i][2] = fmaf(a, v0.z, r[i][2]);
            r[i][3] = fmaf(a, v0.w, r[i][3]);
            r[i][0] = fmaf(b, v1.x, r[i][0]);
            r[i][1] = fmaf(b, v1.y, r[i][1]);
            r[i][2] = fmaf(b, v1.z, r[i][2]);
            r[i][3] = fmaf(b, v1.w, r[i][3]);
        }
    }

    float4 ce = *(const float4*)(CE + jb);
    #pragma unroll
    for (int i = 0; i < IT; ++i) {
        float rc[4] = { r[i][0] + ce.x, r[i][1] + ce.y,
                        r[i][2] + ce.z, r[i][3] + ce.w };
        float M = fmaxf(fmaxf(rc[0], rc[1]), fmaxf(rc[2], rc[3]));
        float S = __builtin_amdgcn_exp2f(rc[0] - M) + __builtin_amdgcn_exp2f(rc[1] - M)
                + __builtin_amdgcn_exp2f(rc[2] - M) + __builtin_amdgcn_exp2f(rc[3] - M);
        RM[i][t] = M;
        RS[i][t] = S;
    }
    __syncthreads();

    for (int s = 128; s > 0; s >>= 1) {
        if (t < s) {
            #pragma unroll
            for (int i = 0; i < IT; ++i) {
                float Ma = RM[i][t], Mb = RM[i][t + s];
                float mn = fmaxf(Ma, Mb);
                RS[i][t] = RS[i][t]     * __builtin_amdgcn_exp2f(Ma - mn)
                         + RS[i][t + s] * __builtin_amdgcn_exp2f(Mb - mn);
                RM[i][t] = mn;
            }
        }
        __syncthreads();
    }
    if (t < IT) {
        ws[OFF_RMP + ph * BATCH + i0 + t] = RM[t][0];
        ws[OFF_RSP + ph * BATCH + i0 + t] = RS[t][0];
    }
}

__global__ __launch_bounds__(256) void finalize1_kernel(const float* __restrict__ ws,
                                                        float* __restrict__ wso) {
    __shared__ float s_tc[256];
    __shared__ float s_kl[256];
    int t = threadIdx.x;
    int i = blockIdx.x * 256 + t;

    const float* __restrict__ P0 = ws + OFF_PP;
    const float* __restrict__ P1 = ws + OFF_PP + 64 * BATCH;

    float sp = 0.0f;
    #pragma unroll 8
    for (int l = 0; l < LATENT; ++l)
        sp += __builtin_amdgcn_logf(P0[l * BATCH + i] + P1[l * BATCH + i]);

    float M0 = ws[OFF_RMP + i], M1 = ws[OFF_RMP + BATCH + i];
    float S0 = ws[OFF_RSP + i], S1 = ws[OFF_RSP + BATCH + i];
    float mn = fmaxf(M0, M1);
    float lqz = mn + __builtin_amdgcn_logf(
        S0 * __builtin_amdgcn_exp2f(M0 - mn) + S1 * __builtin_amdgcn_exp2f(M1 - mn));

    s_tc[t] = lqz - sp;
    s_kl[t] = ws[OFF_KLP + i];
    __syncthreads();
    for (int s = 128; s > 0; s >>= 1) {
        if (t < s) { s_tc[t] += s_tc[t + s]; s_kl[t] += s_kl[t + s]; }
        __syncthreads();
    }
    if (t == 0) {
        wso[OFF_PART + blockIdx.x]     = s_tc[0];
        wso[OFF_PART + 8 + blockIdx.x] = s_kl[0];
    }
}

__global__ void finalize2_kernel(const float* __restrict__ ws,
                                 float* __restrict__ out) {
    if (threadIdx.x == 0) {
        float tc = 0.0f, kl = 0.0f;
        #pragma unroll
        for (int b = 0; b < 8; ++b) {
            tc += ws[OFF_PART + b];
            kl += ws[OFF_PART + 8 + b];
        }
        out[0] = BETA_M1 * (LN2 * tc / (float)BATCH) + 0.5f * (kl / (float)BATCH);
    }
}

extern "C" void kernel_launch(void* const* d_in, const int* in_sizes, int n_in,
                              void* d_out, int out_size, void* d_ws, size_t ws_size,
                              hipStream_t stream) {
    const float* z        = (const float*)d_in[0];
    const float* z_mean   = (const float*)d_in[1];
    const float* z_logvar = (const float*)d_in[2];
    float* out = (float*)d_out;
    float* ws  = (float*)d_ws;

    precompute_kernel<<<BATCH, LATENT, 0, stream>>>(z, z_mean, z_logvar, ws);
    dim_lse_kernel<<<1024, 256, 0, stream>>>(z, ws);
    row_lse_kernel<<<256, 256, 0, stream>>>(ws);
    finalize1_kernel<<<8, 256, 0, stream>>>(ws, ws);
    finalize2_kernel<<<1, 64, 0, stream>>>(ws, out);
}

// Round 4
// 128.625 us; speedup vs baseline: 1.6266x; 1.6266x over previous
//
#include <hip/hip_runtime.h>
#include <hip/hip_bf16.h>
#include <math.h>

#define BATCH 2048
#define LATENT 64
#define LOG_2PI 1.8378770664093453f
#define BETA_M1 5.0f
#define LN2 0.69314718055994530942f
// C2 = -0.5 * log2(e)
#define C2 (-0.72134752044448170368f)

// ws layout (float offsets):
//   Vt   [128][2048]  Vt[2l][j]=C2*inv, Vt[2l+1][j]=C2*m*inv
//   Tce  [64][2048]   Tce[l][j]=C2*(m^2*inv+lv+LOG2PI)
//   Up   [128][2048]  Up[2l][i]=z^2, Up[2l+1][i]=-2z
//   CE   [2048], KLP [2048]
//   RMP/RSP [2][2048] row-LSE partials (log2 domain)
//   PART [16]
//   PP   bf16 [8][64][2048] per-j-chunk raw exp sums (2 MB)
#define OFF_VT   0
#define OFF_TCE  (128*BATCH)
#define OFF_UP   (OFF_TCE + 64*BATCH)
#define OFF_CE   (OFF_UP + 128*BATCH)
#define OFF_KLP  (OFF_CE + BATCH)
#define OFF_RMP  (OFF_KLP + BATCH)
#define OFF_RSP  (OFF_RMP + 2*BATCH)
#define OFF_PART (OFF_RSP + 2*BATCH)
#define OFF_PP   (OFF_PART + 16)

// Transpose-precompute: grid 32 blocks x 256 thr, each block = 64 j, all 64 l.
// Coalesced reads, LDS transpose, coalesced row writes (l-major outputs).
__global__ __launch_bounds__(256) void precompute_kernel(const float* __restrict__ z,
                                                         const float* __restrict__ zm,
                                                         const float* __restrict__ zlv,
                                                         float* __restrict__ ws) {
    __shared__ float Tz[64][65], Tm[64][65], Tlv[64][65];
    __shared__ float CEp[4][64], KLp[4][64];
    int t = threadIdx.x, lane = t & 63, w = t >> 6;
    int j0 = blockIdx.x * 64;

    #pragma unroll
    for (int p = 0; p < 16; ++p) {
        int jr = p * 4 + w;
        int idx = (j0 + jr) * LATENT + lane;
        Tz[jr][lane]  = z[idx];
        Tm[jr][lane]  = zm[idx];
        Tlv[jr][lane] = zlv[idx];
    }
    __syncthreads();

    int j = j0 + lane;
    float ce_acc = 0.0f, kl_acc = 0.0f;
    #pragma unroll
    for (int q = 0; q < 16; ++q) {
        int l = q * 4 + w;
        float zv = Tz[lane][l];
        float m  = Tm[lane][l];
        float lv = Tlv[lane][l];
        float iv  = __expf(-lv);
        float civ = C2 * iv;
        float miv = m * iv;
        float cmv = C2 * miv;
        float cev = C2 * fmaf(m, miv, lv + LOG_2PI);
        ws[OFF_VT  + (2*l)   * BATCH + j] = civ;
        ws[OFF_VT  + (2*l+1) * BATCH + j] = cmv;
        ws[OFF_TCE + l       * BATCH + j] = cev;
        ws[OFF_UP  + (2*l)   * BATCH + j] = zv * zv;
        ws[OFF_UP  + (2*l+1) * BATCH + j] = -2.0f * zv;
        ce_acc += cev;
        kl_acc += fmaf(m, m, __expf(lv)) - lv - 1.0f;
    }
    CEp[w][lane] = ce_acc;
    KLp[w][lane] = kl_acc;
    __syncthreads();
    if (w == 0) {
        ws[OFF_CE  + j] = CEp[0][lane] + CEp[1][lane] + CEp[2][lane] + CEp[3][lane];
        ws[OFF_KLP + j] = KLp[0][lane] + KLp[1][lane] + KLp[2][lane] + KLp[3][lane];
    }
}

// Fused main: blocks [0,1024) = dim-LSE path, [1024,1536) = row-LSE path.
#define DIMB 1024
#define ROWB 512
__global__ __launch_bounds__(256) void main_kernel(float* __restrict__ ws) {
    __shared__ float RMs[8][4], RSs[8][4];
    int bx = blockIdx.x, t = threadIdx.x;

    if (bx < DIMB) {
        // dim path: l = bx>>4, i-chunk = (bx>>3)&1 (1024 i, 4 per thread), j-chunk = bx&7 (256 j)
        int l  = bx >> 4;
        int ic = (bx >> 3) & 1;
        int jc = bx & 7;
        int ib = ic * 1024 + t;

        const float* __restrict__ up0 = ws + OFF_UP + (2*l)   * BATCH;
        const float* __restrict__ up1 = ws + OFF_UP + (2*l+1) * BATCH;
        float z2_0 = up0[ib],       z2_1 = up0[ib + 256],
              z2_2 = up0[ib + 512], z2_3 = up0[ib + 768];
        float n2_0 = up1[ib],       n2_1 = up1[ib + 256],
              n2_2 = up1[ib + 512], n2_3 = up1[ib + 768];

        const float* __restrict__ pc = ws + OFF_VT  + (2*l)   * BATCH + jc * 256;
        const float* __restrict__ pm = ws + OFF_VT  + (2*l+1) * BATCH + jc * 256;
        const float* __restrict__ pe = ws + OFF_TCE + l       * BATCH + jc * 256;

        float s0 = 0.f, s1 = 0.f, s2 = 0.f, s3 = 0.f;
        for (int jj = 0; jj < 256; jj += 8) {
            #pragma unroll
            for (int u = 0; u < 8; ++u) {
                float cc = pc[jj + u];
                float mm = pm[jj + u];
                float ee = pe[jj + u];
                s0 += __builtin_amdgcn_exp2f(fmaf(z2_0, cc, fmaf(n2_0, mm, ee)));
                s1 += __builtin_amdgcn_exp2f(fmaf(z2_1, cc, fmaf(n2_1, mm, ee)));
                s2 += __builtin_amdgcn_exp2f(fmaf(z2_2, cc, fmaf(n2_2, mm, ee)));
                s3 += __builtin_amdgcn_exp2f(fmaf(z2_3, cc, fmaf(n2_3, mm, ee)));
            }
        }
        __hip_bfloat16* pp = (__hip_bfloat16*)(ws + OFF_PP);
        size_t base = ((size_t)(jc * 64 + l)) * BATCH;
        pp[base + ib]       = __float2bfloat16(s0);
        pp[base + ib + 256] = __float2bfloat16(s1);
        pp[base + ib + 512] = __float2bfloat16(s2);
        pp[base + ib + 768] = __float2bfloat16(s3);
    } else {
        // row path: 8 i per block, 4 j per thread over a j-half
        int bx2 = bx - DIMB;
        int ib8 = bx2 >> 1, ph = bx2 & 1;
        int i0 = ib8 * 8;
        int jb = ph * 1024 + 4 * t;
        int lane = t & 63, w = t >> 6;

        const float* __restrict__ Vt = ws + OFF_VT;
        const float* __restrict__ Up = ws + OFF_UP;

        float r[8][4];
        #pragma unroll
        for (int i = 0; i < 8; ++i)
            r[i][0] = r[i][1] = r[i][2] = r[i][3] = 0.0f;

        for (int l = 0; l < LATENT; ++l) {
            float4 v0 = *(const float4*)(Vt + (2*l)   * BATCH + jb);
            float4 v1 = *(const float4*)(Vt + (2*l+1) * BATCH + jb);
            const float* __restrict__ u0 = Up + (2*l)   * BATCH + i0;  // uniform -> s_load
            const float* __restrict__ u1 = Up + (2*l+1) * BATCH + i0;  // uniform -> s_load
            #pragma unroll
            for (int i = 0; i < 8; ++i) {
                float a = u0[i], b = u1[i];
                r[i][0] = fmaf(a, v0.x, fmaf(b, v1.x, r[i][0]));
                r[i][1] = fmaf(a, v0.y, fmaf(b, v1.y, r[i][1]));
                r[i][2] = fmaf(a, v0.z, fmaf(b, v1.z, r[i][2]));
                r[i][3] = fmaf(a, v0.w, fmaf(b, v1.w, r[i][3]));
            }
        }

        float4 ce4 = *(const float4*)(ws + OFF_CE + jb);
        #pragma unroll
        for (int i = 0; i < 8; ++i) {
            float rc0 = r[i][0] + ce4.x, rc1 = r[i][1] + ce4.y;
            float rc2 = r[i][2] + ce4.z, rc3 = r[i][3] + ce4.w;
            float M = fmaxf(fmaxf(rc0, rc1), fmaxf(rc2, rc3));
            float S = __builtin_amdgcn_exp2f(rc0 - M) + __builtin_amdgcn_exp2f(rc1 - M)
                    + __builtin_amdgcn_exp2f(rc2 - M) + __builtin_amdgcn_exp2f(rc3 - M);
            #pragma unroll
            for (int off = 32; off > 0; off >>= 1) {
                float Mo = __shfl_xor(M, off, 64);
                float So = __shfl_xor(S, off, 64);
                float mn = fmaxf(M, Mo);
                S = S * __builtin_amdgcn_exp2f(M - mn) + So * __builtin_amdgcn_exp2f(Mo - mn);
                M = mn;
            }
            if (lane == 0) { RMs[i][w] = M; RSs[i][w] = S; }
        }
        __syncthreads();
        if (t < 8) {
            float M = RMs[t][0], S = RSs[t][0];
            #pragma unroll
            for (int w2 = 1; w2 < 4; ++w2) {
                float Mo = RMs[t][w2], So = RSs[t][w2];
                float mn = fmaxf(M, Mo);
                S = S * __builtin_amdgcn_exp2f(M - mn) + So * __builtin_amdgcn_exp2f(Mo - mn);
                M = mn;
            }
            ws[OFF_RMP + ph * BATCH + i0 + t] = M;
            ws[OFF_RSP + ph * BATCH + i0 + t] = S;
        }
    }
}

__global__ __launch_bounds__(256) void finalize1_kernel(const float* __restrict__ ws,
                                                        float* __restrict__ wso) {
    __shared__ float s_tc[256];
    __shared__ float s_kl[256];
    int t = threadIdx.x;
    int i = blockIdx.x * 256 + t;

    const __hip_bfloat16* __restrict__ pp = (const __hip_bfloat16*)(ws + OFF_PP);
    float sp = 0.0f;
    for (int l = 0; l < LATENT; ++l) {
        float s = 0.0f;
        #pragma unroll
        for (int c = 0; c < 8; ++c)
            s += __bfloat162float(pp[((size_t)(c * 64 + l)) * BATCH + i]);
        sp += __builtin_amdgcn_logf(s);
    }

    float M0 = ws[OFF_RMP + i], M1 = ws[OFF_RMP + BATCH + i];
    float S0 = ws[OFF_RSP + i], S1 = ws[OFF_RSP + BATCH + i];
    float mn = fmaxf(M0, M1);
    float lqz = mn + __builtin_amdgcn_logf(
        S0 * __builtin_amdgcn_exp2f(M0 - mn) + S1 * __builtin_amdgcn_exp2f(M1 - mn));

    s_tc[t] = lqz - sp;
    s_kl[t] = ws[OFF_KLP + i];
    __syncthreads();
    for (int s = 128; s > 0; s >>= 1) {
        if (t < s) { s_tc[t] += s_tc[t + s]; s_kl[t] += s_kl[t + s]; }
        __syncthreads();
    }
    if (t == 0) {
        wso[OFF_PART + blockIdx.x]     = s_tc[0];
        wso[OFF_PART + 8 + blockIdx.x] = s_kl[0];
    }
}

__global__ void finalize2_kernel(const float* __restrict__ ws,
                                 float* __restrict__ out) {
    if (threadIdx.x == 0) {
        float tc = 0.0f, kl = 0.0f;
        #pragma unroll
        for (int b = 0; b < 8; ++b) {
            tc += ws[OFF_PART + b];
            kl += ws[OFF_PART + 8 + b];
        }
        out[0] = BETA_M1 * (LN2 * tc / (float)BATCH) + 0.5f * (kl / (float)BATCH);
    }
}

extern "C" void kernel_launch(void* const* d_in, const int* in_sizes, int n_in,
                              void* d_out, int out_size, void* d_ws, size_t ws_size,
                              hipStream_t stream) {
    const float* z        = (const float*)d_in[0];
    const float* z_mean   = (const float*)d_in[1];
    const float* z_logvar = (const float*)d_in[2];
    float* out = (float*)d_out;
    float* ws  = (float*)d_ws;

    precompute_kernel<<<32, 256, 0, stream>>>(z, z_mean, z_logvar, ws);
    main_kernel<<<DIMB + ROWB, 256, 0, stream>>>(ws);
    finalize1_kernel<<<8, 256, 0, stream>>>(ws, ws);
    finalize2_kernel<<<1, 64, 0, stream>>>(ws, out);
}

// Round 5
// 119.151 us; speedup vs baseline: 1.7560x; 1.0795x over previous
//
#include <hip/hip_runtime.h>
#include <hip/hip_bf16.h>
#include <math.h>

#define BATCH 2048
#define LATENT 64
#define LOG_2PI 1.8378770664093453f
#define BETA_M1 5.0f
#define LN2 0.69314718055994530942f
// C2 = -0.5 * log2(e)
#define C2 (-0.72134752044448170368f)

// ws layout (float offsets):
//   Vt   [128][2048]  Vt[2l][j]=C2*inv, Vt[2l+1][j]=C2*m*inv
//   Tce  [64][2048]   Tce[l][j]=C2*(m^2*inv+lv+LOG2PI)
//   Up   [128][2048]  Up[2l][i]=z^2, Up[2l+1][i]=-2z
//   CE   [2048], KLP [2048]
//   RMP/RSP [2][2048] row-LSE partials (log2 domain)
//   PART [16]         PART[0]=tc sum (atomic), PART[1]=kl sum (atomic)
//   PP   bf16 [8][64][2048] per-j-chunk raw exp sums (2 MB)
#define OFF_VT   0
#define OFF_TCE  (128*BATCH)
#define OFF_UP   (OFF_TCE + 64*BATCH)
#define OFF_CE   (OFF_UP + 128*BATCH)
#define OFF_KLP  (OFF_CE + BATCH)
#define OFF_RMP  (OFF_KLP + BATCH)
#define OFF_RSP  (OFF_RMP + 2*BATCH)
#define OFF_PART (OFF_RSP + 2*BATCH)
#define OFF_PP   (OFF_PART + 16)

// Precompute: grid 128 x 256, each block transposes 16 j x 64 l.
__global__ __launch_bounds__(256) void precompute_kernel(const float* __restrict__ z,
                                                         const float* __restrict__ zm,
                                                         const float* __restrict__ zlv,
                                                         float* __restrict__ ws) {
    __shared__ float Tz[16][65], Tm[16][65], Tlv[16][65];
    __shared__ float CEp[16][16], KLp[16][16];
    int t = threadIdx.x, lane = t & 63, w = t >> 6;
    int j0 = blockIdx.x * 16;

    #pragma unroll
    for (int p = 0; p < 4; ++p) {
        int jr = p * 4 + w;
        int idx = (j0 + jr) * LATENT + lane;
        Tz[jr][lane]  = z[idx];
        Tm[jr][lane]  = zm[idx];
        Tlv[jr][lane] = zlv[idx];
    }
    if (blockIdx.x == 0 && t < 16) ws[OFF_PART + t] = 0.0f;
    __syncthreads();

    int jl = t & 15, lg = t >> 4;
    int j = j0 + jl;
    float ce_acc = 0.0f, kl_acc = 0.0f;
    #pragma unroll
    for (int q = 0; q < 4; ++q) {
        int l = q * 16 + lg;
        float zv = Tz[jl][l];
        float m  = Tm[jl][l];
        float lv = Tlv[jl][l];
        float iv  = __expf(-lv);
        float civ = C2 * iv;
        float miv = m * iv;
        float cmv = C2 * miv;
        float cev = C2 * fmaf(m, miv, lv + LOG_2PI);
        ws[OFF_VT  + (2*l)   * BATCH + j] = civ;
        ws[OFF_VT  + (2*l+1) * BATCH + j] = cmv;
        ws[OFF_TCE + l       * BATCH + j] = cev;
        ws[OFF_UP  + (2*l)   * BATCH + j] = zv * zv;
        ws[OFF_UP  + (2*l+1) * BATCH + j] = -2.0f * zv;
        ce_acc += cev;
        kl_acc += fmaf(m, m, __expf(lv)) - lv - 1.0f;
    }
    CEp[lg][jl] = ce_acc;
    KLp[lg][jl] = kl_acc;
    __syncthreads();
    if (t < 16) {
        float ce = 0.0f, kl = 0.0f;
        #pragma unroll
        for (int g = 0; g < 16; ++g) { ce += CEp[g][t]; kl += KLp[g][t]; }
        ws[OFF_CE  + j0 + t] = ce;
        ws[OFF_KLP + j0 + t] = kl;
    }
}

// Fused main: blocks [0,512) dim path (8 i/thread, all 2048 i, 256-j chunk),
//             blocks [512,1024) row path.
#define DIMB 512
#define ROWB 512
__global__ __launch_bounds__(256) void main_kernel(float* __restrict__ ws) {
    __shared__ float RMs[8][4], RSs[8][4];
    int bx = blockIdx.x, t = threadIdx.x;

    if (bx < DIMB) {
        int l  = bx >> 3;
        int jc = bx & 7;

        const float* __restrict__ up0 = ws + OFF_UP + (2*l)   * BATCH;
        const float* __restrict__ up1 = ws + OFF_UP + (2*l+1) * BATCH;
        float z2[8], n2[8];
        #pragma unroll
        for (int k = 0; k < 8; ++k) {
            z2[k] = up0[t + 256*k];
            n2[k] = up1[t + 256*k];
        }

        const float* __restrict__ pc = ws + OFF_VT  + (2*l)   * BATCH + jc * 256;
        const float* __restrict__ pm = ws + OFF_VT  + (2*l+1) * BATCH + jc * 256;
        const float* __restrict__ pe = ws + OFF_TCE + l       * BATCH + jc * 256;

        float s[8];
        #pragma unroll
        for (int k = 0; k < 8; ++k) s[k] = 0.0f;

        for (int jj = 0; jj < 256; jj += 8) {
            #pragma unroll
            for (int u = 0; u < 8; ++u) {
                float cc = pc[jj + u];
                float mm = pm[jj + u];
                float ee = pe[jj + u];
                #pragma unroll
                for (int k = 0; k < 8; ++k)
                    s[k] += __builtin_amdgcn_exp2f(fmaf(z2[k], cc, fmaf(n2[k], mm, ee)));
            }
        }

        __hip_bfloat16* pp = (__hip_bfloat16*)(ws + OFF_PP);
        size_t base = ((size_t)(jc * 64 + l)) * BATCH;
        #pragma unroll
        for (int k = 0; k < 8; ++k)
            pp[base + t + 256*k] = __float2bfloat16(s[k]);
    } else {
        // row path: 8 i per block, 4 j per thread over a j-half
        int bx2 = bx - DIMB;
        int ib8 = bx2 >> 1, ph = bx2 & 1;
        int i0 = ib8 * 8;
        int jb = ph * 1024 + 4 * t;
        int lane = t & 63, w = t >> 6;

        const float* __restrict__ Vt = ws + OFF_VT;
        const float* __restrict__ Up = ws + OFF_UP;

        float r[8][4];
        #pragma unroll
        for (int i = 0; i < 8; ++i)
            r[i][0] = r[i][1] = r[i][2] = r[i][3] = 0.0f;

        for (int l = 0; l < LATENT; ++l) {
            float4 v0 = *(const float4*)(Vt + (2*l)   * BATCH + jb);
            float4 v1 = *(const float4*)(Vt + (2*l+1) * BATCH + jb);
            const float* __restrict__ u0 = Up + (2*l)   * BATCH + i0;  // uniform -> s_load
            const float* __restrict__ u1 = Up + (2*l+1) * BATCH + i0;  // uniform -> s_load
            #pragma unroll
            for (int i = 0; i < 8; ++i) {
                float a = u0[i], b = u1[i];
                r[i][0] = fmaf(a, v0.x, fmaf(b, v1.x, r[i][0]));
                r[i][1] = fmaf(a, v0.y, fmaf(b, v1.y, r[i][1]));
                r[i][2] = fmaf(a, v0.z, fmaf(b, v1.z, r[i][2]));
                r[i][3] = fmaf(a, v0.w, fmaf(b, v1.w, r[i][3]));
            }
        }

        float4 ce4 = *(const float4*)(ws + OFF_CE + jb);
        #pragma unroll
        for (int i = 0; i < 8; ++i) {
            float rc0 = r[i][0] + ce4.x, rc1 = r[i][1] + ce4.y;
            float rc2 = r[i][2] + ce4.z, rc3 = r[i][3] + ce4.w;
            float M = fmaxf(fmaxf(rc0, rc1), fmaxf(rc2, rc3));
            float S = __builtin_amdgcn_exp2f(rc0 - M) + __builtin_amdgcn_exp2f(rc1 - M)
                    + __builtin_amdgcn_exp2f(rc2 - M) + __builtin_amdgcn_exp2f(rc3 - M);
            #pragma unroll
            for (int off = 32; off > 0; off >>= 1) {
                float Mo = __shfl_xor(M, off, 64);
                float So = __shfl_xor(S, off, 64);
                float mn = fmaxf(M, Mo);
                S = S * __builtin_amdgcn_exp2f(M - mn) + So * __builtin_amdgcn_exp2f(Mo - mn);
                M = mn;
            }
            if (lane == 0) { RMs[i][w] = M; RSs[i][w] = S; }
        }
        __syncthreads();
        if (t < 8) {
            float M = RMs[t][0], S = RSs[t][0];
            #pragma unroll
            for (int w2 = 1; w2 < 4; ++w2) {
                float Mo = RMs[t][w2], So = RSs[t][w2];
                float mn = fmaxf(M, Mo);
                S = S * __builtin_amdgcn_exp2f(M - mn) + So * __builtin_amdgcn_exp2f(Mo - mn);
                M = mn;
            }
            ws[OFF_RMP + ph * BATCH + i0 + t] = M;
            ws[OFF_RSP + ph * BATCH + i0 + t] = S;
        }
    }
}

// Flat reduction: tc = sum_i lqz_i - sum_{i,l} log2(s_il); kl = sum_i KLP[i].
// Grid 128 x 256: 32768 threads, 4 (l,i) elements each; first 2048 threads
// also handle the per-i lqz / KL terms. One atomicAdd pair per block.
__global__ __launch_bounds__(256) void finalize_kernel(float* __restrict__ ws) {
    __shared__ float s_tc[256];
    __shared__ float s_kl[256];
    int t = threadIdx.x;
    int gid = blockIdx.x * 256 + t;

    const __hip_bfloat16* __restrict__ pp = (const __hip_bfloat16*)(ws + OFF_PP);

    float acc = 0.0f, kl = 0.0f;
    #pragma unroll
    for (int k = 0; k < 4; ++k) {
        int f = gid + 32768 * k;          // 0..131071
        int l = f >> 11, i = f & 2047;
        float s = 0.0f;
        #pragma unroll
        for (int c = 0; c < 8; ++c)
            s += __bfloat162float(pp[((size_t)(c * 64 + l)) * BATCH + i]);
        acc -= __builtin_amdgcn_logf(s);  // -sum log2 terms
    }

    if (gid < BATCH) {
        int i = gid;
        float M0 = ws[OFF_RMP + i], M1 = ws[OFF_RMP + BATCH + i];
        float S0 = ws[OFF_RSP + i], S1 = ws[OFF_RSP + BATCH + i];
        float mn = fmaxf(M0, M1);
        acc += mn + __builtin_amdgcn_logf(
            S0 * __builtin_amdgcn_exp2f(M0 - mn) + S1 * __builtin_amdgcn_exp2f(M1 - mn));
        kl = ws[OFF_KLP + i];
    }

    s_tc[t] = acc; s_kl[t] = kl;
    __syncthreads();
    for (int s = 128; s > 0; s >>= 1) {
        if (t < s) { s_tc[t] += s_tc[t + s]; s_kl[t] += s_kl[t + s]; }
        __syncthreads();
    }
    if (t == 0) {
        atomicAdd(&ws[OFF_PART + 0], s_tc[0]);
        atomicAdd(&ws[OFF_PART + 1], s_kl[0]);
    }
}

__global__ void assemble_kernel(const float* __restrict__ ws,
                                float* __restrict__ out) {
    if (threadIdx.x == 0) {
        float tc = ws[OFF_PART + 0];
        float kl = ws[OFF_PART + 1];
        out[0] = BETA_M1 * (LN2 * tc / (float)BATCH) + 0.5f * (kl / (float)BATCH);
    }
}

extern "C" void kernel_launch(void* const* d_in, const int* in_sizes, int n_in,
                              void* d_out, int out_size, void* d_ws, size_t ws_size,
                              hipStream_t stream) {
    const float* z        = (const float*)d_in[0];
    const float* z_mean   = (const float*)d_in[1];
    const float* z_logvar = (const float*)d_in[2];
    float* out = (float*)d_out;
    float* ws  = (float*)d_ws;

    precompute_kernel<<<128, 256, 0, stream>>>(z, z_mean, z_logvar, ws);
    main_kernel<<<DIMB + ROWB, 256, 0, stream>>>(ws);
    finalize_kernel<<<128, 256, 0, stream>>>(ws);
    assemble_kernel<<<1, 64, 0, stream>>>(ws, out);
}